// Round 1
// baseline (845.162 us; speedup 1.0000x reference)
//
#include <hip/hip_runtime.h>
#include <hip/hip_cooperative_groups.h>
#include <math.h>

namespace cg = cooperative_groups;

#define HID 64
#define HEADS 8
#define NUM_LAYERS 3
#define ALD 72

typedef __attribute__((ext_vector_type(8))) short bf16x8;
typedef __attribute__((ext_vector_type(4))) float f32x4;

// ---------------------------------------------------------------------------
// bf16 helpers (storage compression; accumulation stays f32)
// ---------------------------------------------------------------------------
__device__ __forceinline__ unsigned short f2bf(float f) {
    union { float f; unsigned int u; } cv; cv.f = f;
    unsigned int u = cv.u;
    unsigned int r = (u + 0x7FFFu + ((u >> 16) & 1u)) >> 16;  // RNE
    return (unsigned short)r;
}
__device__ __forceinline__ float bflo(unsigned int u) {
    union { unsigned int u; float f; } cv; cv.u = u << 16; return cv.f;
}
__device__ __forceinline__ float bfhi(unsigned int u) {
    union { unsigned int u; float f; } cv; cv.u = u & 0xFFFF0000u; return cv.f;
}
__device__ __forceinline__ unsigned relu_pk(unsigned u) {  // relu on 2 packed bf16
    unsigned m = ((u & 0x8000u) ? 0u : 0xFFFFu) |
                 ((u & 0x80000000u) ? 0u : 0xFFFF0000u);
    return u & m;
}

// ---------------------------------------------------------------------------
// MFMA GEMM core: block = 64 nodes x 64 oc, 4 waves, wave w = 16-row strip.
// A in LDS row-major bf16 (stride 72); W in LDS transposed bf16 [n][k].
// ---------------------------------------------------------------------------
__device__ __forceinline__ void stage_w_bf16(unsigned short* Wt,
                                             const float* __restrict__ w, int tid) {
    for (int idx = tid; idx < 1024; idx += 256) {
        int k = idx >> 4, n4 = (idx & 15) * 4;
        float4 wv = *(const float4*)&w[k * 64 + n4];
        Wt[(n4 + 0) * ALD + k] = f2bf(wv.x);
        Wt[(n4 + 1) * ALD + k] = f2bf(wv.y);
        Wt[(n4 + 2) * ALD + k] = f2bf(wv.z);
        Wt[(n4 + 3) * ALD + k] = f2bf(wv.w);
    }
}

__device__ __forceinline__ void mfma_step(const unsigned short* Alds,
                                          const unsigned short* Wt,
                                          int tid, f32x4 acc[4]) {
    int lane = tid & 63;
    int m0 = (tid >> 6) * 16;
    int c16 = lane & 15, quad = lane >> 4;
    const unsigned short* ar = &Alds[(m0 + c16) * ALD + quad * 8];
    bf16x8 a0 = *(const bf16x8*)ar;
    bf16x8 a1 = *(const bf16x8*)(ar + 32);
#pragma unroll
    for (int nt = 0; nt < 4; ++nt) {
        const unsigned short* br = &Wt[(nt * 16 + c16) * ALD + quad * 8];
        bf16x8 b0 = *(const bf16x8*)br;
        bf16x8 b1 = *(const bf16x8*)(br + 32);
        acc[nt] = __builtin_amdgcn_mfma_f32_16x16x32_bf16(a0, b0, acc[nt], 0, 0, 0);
        acc[nt] = __builtin_amdgcn_mfma_f32_16x16x32_bf16(a1, b1, acc[nt], 0, 0, 0);
    }
}

// ---------------------------------------------------------------------------
// Tile bodies (shared between mega-kernel and fallback kernels)
// ---------------------------------------------------------------------------
// qkv-style 64x64 GEMM tile: bf16 src (optional input relu) @ W + b.
// qd != nullptr -> write f32 q; else bf16 into kvdst at [node*kv_stride+kv_off].
__device__ __forceinline__ void qkv_tile_body(
    const unsigned short* __restrict__ src, const float* __restrict__ w,
    const float* __restrict__ b, float* __restrict__ qd,
    unsigned short* __restrict__ kvdst, int kv_stride, int kv_off, bool relu_in,
    int node0, int n, int tid, unsigned short* Alds, unsigned short* Wt) {
    stage_w_bf16(Wt, w, tid);
    for (int idx = tid; idx < 512; idx += 256) {
        int r = idx >> 3, seg = idx & 7;
        int node = node0 + r;
        uint4 u = make_uint4(0u, 0u, 0u, 0u);
        if (node < n) u = *(const uint4*)&src[(size_t)node * 64 + seg * 8];
        if (relu_in) {
            u.x = relu_pk(u.x); u.y = relu_pk(u.y);
            u.z = relu_pk(u.z); u.w = relu_pk(u.w);
        }
        *(uint4*)&Alds[r * ALD + seg * 8] = u;
    }
    __syncthreads();
    f32x4 acc[4];
#pragma unroll
    for (int nt = 0; nt < 4; ++nt) acc[nt] = (f32x4){0.f, 0.f, 0.f, 0.f};
    mfma_step(Alds, Wt, tid, acc);

    int lane = tid & 63;
    int m0 = (tid >> 6) * 16, c16 = lane & 15, quad = lane >> 4;
    float bias[4];
#pragma unroll
    for (int nt = 0; nt < 4; ++nt) bias[nt] = b[nt * 16 + c16];
    if (qd) {
#pragma unroll
        for (int i = 0; i < 4; ++i) {
            int node = node0 + m0 + quad * 4 + i;
            if (node < n) {
#pragma unroll
                for (int nt = 0; nt < 4; ++nt)
                    qd[(size_t)node * 64 + nt * 16 + c16] = acc[nt][i] + bias[nt];
            }
        }
    } else {
#pragma unroll
        for (int i = 0; i < 4; ++i) {
            int node = node0 + m0 + quad * 4 + i;
            if (node < n) {
#pragma unroll
                for (int nt = 0; nt < 4; ++nt)
                    kvdst[(size_t)node * kv_stride + kv_off + nt * 16 + c16] =
                        f2bf(acc[nt][i] + bias[nt]);
            }
        }
    }
}

// lin1 tile: h = relu(x@W1+b1) -> bf16 h; V0 = h@Wv0 + bv0 -> bf16 kv0 (stride 64)
__device__ __forceinline__ void lin1_tile_body(
    const float* __restrict__ x, const float* __restrict__ w,
    const float* __restrict__ b, const float* __restrict__ wv0,
    const float* __restrict__ bv0, unsigned short* __restrict__ h,
    unsigned short* __restrict__ kv, int n, int node0, int tid,
    unsigned short* Alds, unsigned short* Wt) {
    f32x4 acc[4];
#pragma unroll
    for (int nt = 0; nt < 4; ++nt) acc[nt] = (f32x4){0.f, 0.f, 0.f, 0.f};

    for (int kc = 0; kc < 256; kc += 64) {
        __syncthreads();
        stage_w_bf16(Wt, w + kc * 64, tid);
        for (int idx = tid; idx < 1024; idx += 256) {
            int r = idx >> 4, c4 = (idx & 15) * 4;
            int node = node0 + r;
            float4 v = make_float4(0.f, 0.f, 0.f, 0.f);
            if (node < n) v = *(const float4*)&x[(size_t)node * 256 + kc + c4];
            Alds[r * ALD + c4 + 0] = f2bf(v.x);
            Alds[r * ALD + c4 + 1] = f2bf(v.y);
            Alds[r * ALD + c4 + 2] = f2bf(v.z);
            Alds[r * ALD + c4 + 3] = f2bf(v.w);
        }
        __syncthreads();
        mfma_step(Alds, Wt, tid, acc);
    }
    int lane = tid & 63;
    int m0 = (tid >> 6) * 16, c16 = lane & 15, quad = lane >> 4;
    float bias[4];
#pragma unroll
    for (int nt = 0; nt < 4; ++nt) bias[nt] = b[nt * 16 + c16];

    __syncthreads();  // all waves done reading LDS from last chunk
    stage_w_bf16(Wt, wv0, tid);
#pragma unroll
    for (int i = 0; i < 4; ++i) {
        int row = m0 + quad * 4 + i;
        int node = node0 + row;
#pragma unroll
        for (int nt = 0; nt < 4; ++nt) {
            unsigned short hb = f2bf(fmaxf(acc[nt][i] + bias[nt], 0.f));
            Alds[row * ALD + nt * 16 + c16] = hb;
            if (node < n) h[(size_t)node * 64 + nt * 16 + c16] = hb;
        }
    }
    __syncthreads();
    f32x4 acc2[4];
#pragma unroll
    for (int nt = 0; nt < 4; ++nt) acc2[nt] = (f32x4){0.f, 0.f, 0.f, 0.f};
    mfma_step(Alds, Wt, tid, acc2);
    float bias2[4];
#pragma unroll
    for (int nt = 0; nt < 4; ++nt) bias2[nt] = bv0[nt * 16 + c16];
#pragma unroll
    for (int i = 0; i < 4; ++i) {
        int node = node0 + m0 + quad * 4 + i;
        if (node < n) {
#pragma unroll
            for (int nt = 0; nt < 4; ++nt)
                kv[(size_t)node * 64 + nt * 16 + c16] = f2bf(acc2[nt][i] + bias2[nt]);
        }
    }
}

// 256-thread single-block exclusive-scan over counts -> start, dinv
__device__ __forceinline__ void scan256_body(const int* __restrict__ counts,
                                             int* __restrict__ start,
                                             float* __restrict__ dinv, int n,
                                             int tid, int* sscan) {
    int lane = tid & 63, wvi = tid >> 6;
    int ipt = (n + 255) >> 8;
    int c0 = tid * ipt;
    int c1 = min(n, c0 + ipt);
    int s = 0;
    for (int i = c0; i < c1; ++i) s += counts[i];
    int x = s;
#pragma unroll
    for (int off = 1; off < 64; off <<= 1) {
        int y = __shfl_up(x, off);
        if (lane >= off) x += y;
    }
    if (lane == 63) sscan[wvi] = x;
    __syncthreads();
    if (tid == 0) {
        int r = 0;
#pragma unroll
        for (int i = 0; i < 4; ++i) { int t = sscan[i]; sscan[i + 4] = r; r += t; }
        start[n] = r;
    }
    __syncthreads();
    int run = sscan[wvi + 4] + (x - s);  // exclusive prefix at c0
    for (int i = c0; i < c1; ++i) {
        int v = counts[i];
        start[i] = run;
        dinv[i] = rsqrtf((float)(v + 1));  // +1 self-loop
        run += v;
    }
}

// ---------------------------------------------------------------------------
// attention + aggregate body, CSR by destination.  One wave per node.
// Lane = (edge-slot g = lane>>3, head h = lane&7).
// ---------------------------------------------------------------------------
template <int T>
__device__ __forceinline__ void attn_body(
    int node, int lane, const int* __restrict__ start, const int* __restrict__ ebuf,
    const float* __restrict__ dinv, const float* __restrict__ q,
    const unsigned short* __restrict__ kv, unsigned short* __restrict__ outp) {
    const int KVS = (T == 1) ? 64 : T * 128;
    int g = lane >> 3;
    int cb = (lane & 7) * 8;
    const float isd = 0.35355339059327373f;  // 1/sqrt(8)

    float qv[8];
    if (T > 1) {
        float4 q0 = *(const float4*)&q[(size_t)node * 64 + cb];
        float4 q1 = *(const float4*)&q[(size_t)node * 64 + cb + 4];
        qv[0] = q0.x; qv[1] = q0.y; qv[2] = q0.z; qv[3] = q0.w;
        qv[4] = q1.x; qv[5] = q1.y; qv[6] = q1.z; qv[7] = q1.w;
    }
    float dc = dinv[node];
    int s0 = start[node];
    int cnt = start[node + 1] - s0 + 1;

    float acc[8];
#pragma unroll
    for (int k = 0; k < 8; ++k) acc[k] = 0.f;

    for (int base = 0; base < cnt; base += 8) {
        int idx = base + g;
        bool valid = idx < cnt;
        int r = node;
        if (valid && idx > 0) r = ebuf[s0 + idx - 1];
        float dr = valid ? dinv[r] : 0.f;
        const unsigned short* rkv = kv + (size_t)r * KVS;

        float sc[T];
        float wgt;
        if (T > 1) {
            float m = -1e30f;
#pragma unroll
            for (int s = 0; s < T; ++s) {
                uint4 ku = *(const uint4*)&rkv[s * 128 + cb];
                float p = qv[0] * bflo(ku.x) + qv[1] * bfhi(ku.x)
                        + qv[2] * bflo(ku.y) + qv[3] * bfhi(ku.y)
                        + qv[4] * bflo(ku.z) + qv[5] * bfhi(ku.z)
                        + qv[6] * bflo(ku.w) + qv[7] * bfhi(ku.w);
                p *= isd;
                sc[s] = p;
                m = fmaxf(m, p);
            }
            float denom = 0.f;
#pragma unroll
            for (int s = 0; s < T; ++s) { sc[s] = __expf(sc[s] - m); denom += sc[s]; }
            wgt = dr / denom;
        } else {
            sc[0] = 1.f;
            wgt = dr;
        }

        float mg[8];
#pragma unroll
        for (int k = 0; k < 8; ++k) mg[k] = 0.f;
#pragma unroll
        for (int s = 0; s < T; ++s) {
            uint4 vu = *(const uint4*)&rkv[((T == 1) ? 0 : s * 128 + 64) + cb];
            float wv_ = sc[s];
            mg[0] += wv_ * bflo(vu.x); mg[1] += wv_ * bfhi(vu.x);
            mg[2] += wv_ * bflo(vu.y); mg[3] += wv_ * bfhi(vu.y);
            mg[4] += wv_ * bflo(vu.z); mg[5] += wv_ * bfhi(vu.z);
            mg[6] += wv_ * bflo(vu.w); mg[7] += wv_ * bfhi(vu.w);
        }
#pragma unroll
        for (int k = 0; k < 8; ++k) acc[k] += wgt * mg[k];
    }

#pragma unroll
    for (int off = 8; off < 64; off <<= 1) {
#pragma unroll
        for (int k = 0; k < 8; ++k) acc[k] += __shfl_xor(acc[k], off);
    }
    if (g == 0) {
        ushort4 o0, o1;
        o0.x = f2bf(acc[0] * dc); o0.y = f2bf(acc[1] * dc);
        o0.z = f2bf(acc[2] * dc); o0.w = f2bf(acc[3] * dc);
        o1.x = f2bf(acc[4] * dc); o1.y = f2bf(acc[5] * dc);
        o1.z = f2bf(acc[6] * dc); o1.w = f2bf(acc[7] * dc);
        *(ushort4*)&outp[(size_t)node * 64 + cb] = o0;
        *(ushort4*)&outp[(size_t)node * 64 + cb + 4] = o1;
    }
}

// layer-2 attention fused with final projection + log_softmax
__device__ __forceinline__ void attn3_body(
    int node, int lane, const int* __restrict__ start, const int* __restrict__ ebuf,
    const float* __restrict__ dinv, const float* __restrict__ q,
    const unsigned short* __restrict__ kv, const float* __restrict__ w2,
    const float* __restrict__ b2, float* __restrict__ outp) {
    const int T = 3, KVS = 384;
    int g = lane >> 3;
    int cb = (lane & 7) * 8;
    const float isd = 0.35355339059327373f;

    float qv[8];
    {
        float4 q0 = *(const float4*)&q[(size_t)node * 64 + cb];
        float4 q1 = *(const float4*)&q[(size_t)node * 64 + cb + 4];
        qv[0] = q0.x; qv[1] = q0.y; qv[2] = q0.z; qv[3] = q0.w;
        qv[4] = q1.x; qv[5] = q1.y; qv[6] = q1.z; qv[7] = q1.w;
    }
    float dc = dinv[node];
    int s0 = start[node];
    int cnt = start[node + 1] - s0 + 1;

    float acc[8];
#pragma unroll
    for (int k = 0; k < 8; ++k) acc[k] = 0.f;

    for (int base = 0; base < cnt; base += 8) {
        int idx = base + g;
        bool valid = idx < cnt;
        int r = node;
        if (valid && idx > 0) r = ebuf[s0 + idx - 1];
        float dr = valid ? dinv[r] : 0.f;
        const unsigned short* rkv = kv + (size_t)r * KVS;

        float sc[T];
        float m = -1e30f;
#pragma unroll
        for (int s = 0; s < T; ++s) {
            uint4 ku = *(const uint4*)&rkv[s * 128 + cb];
            float p = qv[0] * bflo(ku.x) + qv[1] * bfhi(ku.x)
                    + qv[2] * bflo(ku.y) + qv[3] * bfhi(ku.y)
                    + qv[4] * bflo(ku.z) + qv[5] * bfhi(ku.z)
                    + qv[6] * bflo(ku.w) + qv[7] * bfhi(ku.w);
            p *= isd;
            sc[s] = p;
            m = fmaxf(m, p);
        }
        float denom = 0.f;
#pragma unroll
        for (int s = 0; s < T; ++s) { sc[s] = __expf(sc[s] - m); denom += sc[s]; }
        float wgt = dr / denom;

        float mg[8];
#pragma unroll
        for (int k = 0; k < 8; ++k) mg[k] = 0.f;
#pragma unroll
        for (int s = 0; s < T; ++s) {
            uint4 vu = *(const uint4*)&rkv[s * 128 + 64 + cb];
            float wv_ = sc[s];
            mg[0] += wv_ * bflo(vu.x); mg[1] += wv_ * bfhi(vu.x);
            mg[2] += wv_ * bflo(vu.y); mg[3] += wv_ * bfhi(vu.y);
            mg[4] += wv_ * bflo(vu.z); mg[5] += wv_ * bfhi(vu.z);
            mg[6] += wv_ * bflo(vu.w); mg[7] += wv_ * bfhi(vu.w);
        }
#pragma unroll
        for (int k = 0; k < 8; ++k) acc[k] += wgt * mg[k];
    }

#pragma unroll
    for (int off = 8; off < 64; off <<= 1) {
#pragma unroll
        for (int k = 0; k < 8; ++k) acc[k] += __shfl_xor(acc[k], off);
    }
    // fused final projection + log_softmax
    float lg = b2[lane];
#pragma unroll
    for (int c = 0; c < 64; ++c) {
        float xc = fmaxf(__shfl(acc[c & 7], c >> 3) * dc, 0.f);
        lg += xc * w2[c * 64 + lane];
    }
    float mx = lg;
#pragma unroll
    for (int off = 1; off < 64; off <<= 1) mx = fmaxf(mx, __shfl_xor(mx, off));
    float e = __expf(lg - mx);
    float ssum = e;
#pragma unroll
    for (int off = 1; off < 64; off <<= 1) ssum += __shfl_xor(ssum, off);
    outp[(size_t)node * 64 + lane] = lg - mx - __logf(ssum);
}

// ---------------------------------------------------------------------------
// MEGA: whole pipeline in ONE cooperative kernel.  Phases:
//  P0 zero counts/fill | P1 lin1 (+fused V0) PARALLEL edge-count |
//  P2 scan (block 0) PARALLEL l1/l2 slice-0 K/V GEMMs | P3 scatter |
//  P4 attn L0 | P5 q1 + l1/l2 slice-1 K/V | P6 attn L1 |
//  P7 q2 + l2 slice-2 K/V | P8 attn L2 + final projection
// ---------------------------------------------------------------------------
__global__ __launch_bounds__(256, 4) void k_mega(
    const float* __restrict__ x, const int* __restrict__ ei,
    const float* __restrict__ w1, const float* __restrict__ b1,
    const float* __restrict__ wq, const float* __restrict__ bq,
    const float* __restrict__ wk, const float* __restrict__ bk,
    const float* __restrict__ wv, const float* __restrict__ bv,
    const float* __restrict__ w2, const float* __restrict__ b2,
    float* __restrict__ outp, float* __restrict__ dinv, float* __restrict__ qbuf,
    unsigned short* __restrict__ xsU, unsigned short* __restrict__ kv0,
    unsigned short* __restrict__ kv1, unsigned short* __restrict__ kv2,
    int* __restrict__ counts, int* __restrict__ fill, int* __restrict__ startA,
    int* __restrict__ ebuf, int n, int E) {
    cg::grid_group grid = cg::this_grid();
    __shared__ __align__(16) unsigned short Alds[64 * ALD];
    __shared__ __align__(16) unsigned short Wt[64 * ALD];
    __shared__ int sscan[8];
    const int tid = threadIdx.x;
    const int bid = blockIdx.x;
    const int NB = gridDim.x;
    const int NT = (n + 63) >> 6;
    const int lane = tid & 63;
    const int wid = (bid << 2) + (tid >> 6);
    const int nw = NB << 2;

    // ---- P0: zero counts + fill ----
    for (int i = bid * 256 + tid; i < n; i += NB * 256) counts[i] = 0;
    for (int i = bid * 256 + tid; i < n; i += NB * 256) fill[i] = 0;
    grid.sync();

    // ---- P1: lin1 (blocks < L1B)  ||  edge count (blocks >= L1B) ----
    {
        int l1b = (NB * 3) >> 2;
        int L1B = NT < l1b ? NT : l1b;
        if (L1B < 1) L1B = 1;
        if (bid < L1B) {
            for (int t = bid; t < NT; t += L1B)
                lin1_tile_body(x, w1, b1, wv, bv, xsU, kv0, n, t << 6, tid, Alds, Wt);
        } else {
            int cb = bid - L1B, ncb = NB - L1B;
            for (int e = cb * 256 + tid; e < E; e += ncb * 256)
                atomicAdd(&counts[ei[E + e]], 1);
        }
    }
    grid.sync();

    // ---- P2: scan (block 0)  ||  K0/V0 for layers 1,2 (blocks >= 1) ----
    if (bid == 0) {
        scan256_body(counts, startA, dinv, n, tid, sscan);
    } else {
        for (int t = bid - 1; t < 4 * NT; t += NB - 1) {
            int job = t / NT, tile = t - job * NT;
            const float* w; const float* b; unsigned short* dst; int stride, koff;
            if (job == 0)      { w = wk + 4096; b = bk + 64;  dst = kv1; stride = 256; koff = 0;  }
            else if (job == 1) { w = wv + 4096; b = bv + 64;  dst = kv1; stride = 256; koff = 64; }
            else if (job == 2) { w = wk + 8192; b = bk + 128; dst = kv2; stride = 384; koff = 0;  }
            else               { w = wv + 8192; b = bv + 128; dst = kv2; stride = 384; koff = 64; }
            __syncthreads();
            qkv_tile_body(xsU, w, b, nullptr, dst, stride, koff, false,
                          tile << 6, n, tid, Alds, Wt);
        }
    }
    grid.sync();

    // ---- P3: scatter ----
    for (int e = bid * 256 + tid; e < E; e += NB * 256) {
        int r = ei[e], c = ei[E + e];
        int pos = startA[c] + atomicAdd(&fill[c], 1);
        ebuf[pos] = r;
    }
    grid.sync();

    // ---- P4: attn layer 0 (T=1) -> xs slice 1 ----
    for (int node = wid; node < n; node += nw)
        attn_body<1>(node, lane, startA, ebuf, dinv, qbuf, kv0, xsU + (size_t)n * 64);
    grid.sync();

    // ---- P5: q1 + slice-1 K/V for layers 1,2 ----
    {
        const unsigned short* xs1 = xsU + (size_t)n * 64;
        for (int t = bid; t < 5 * NT; t += NB) {
            int job = t / NT, tile = t - job * NT;
            const float* w; const float* b;
            float* qd = nullptr; unsigned short* dst = nullptr;
            int stride = 0, koff = 0;
            if (job == 0)      { w = wq + 4096; b = bq + 64; qd = qbuf; }
            else if (job == 1) { w = wk + 4096; b = bk + 64;  dst = kv1; stride = 256; koff = 128; }
            else if (job == 2) { w = wv + 4096; b = bv + 64;  dst = kv1; stride = 256; koff = 192; }
            else if (job == 3) { w = wk + 8192; b = bk + 128; dst = kv2; stride = 384; koff = 128; }
            else               { w = wv + 8192; b = bv + 128; dst = kv2; stride = 384; koff = 192; }
            __syncthreads();
            qkv_tile_body(xs1, w, b, qd, dst, stride, koff, true,
                          tile << 6, n, tid, Alds, Wt);
        }
    }
    grid.sync();

    // ---- P6: attn layer 1 (T=2) -> xs slice 2 ----
    for (int node = wid; node < n; node += nw)
        attn_body<2>(node, lane, startA, ebuf, dinv, qbuf, kv1, xsU + (size_t)n * 128);
    grid.sync();

    // ---- P7: q2 + slice-2 K/V for layer 2 ----
    {
        const unsigned short* xs2 = xsU + (size_t)n * 128;
        for (int t = bid; t < 3 * NT; t += NB) {
            int job = t / NT, tile = t - job * NT;
            const float* w; const float* b;
            float* qd = nullptr; unsigned short* dst = nullptr;
            int stride = 0, koff = 0;
            if (job == 0)      { w = wq + 8192; b = bq + 128; qd = qbuf; }
            else if (job == 1) { w = wk + 8192; b = bk + 128; dst = kv2; stride = 384; koff = 256; }
            else               { w = wv + 8192; b = bv + 128; dst = kv2; stride = 384; koff = 320; }
            __syncthreads();
            qkv_tile_body(xs2, w, b, qd, dst, stride, koff, true,
                          tile << 6, n, tid, Alds, Wt);
        }
    }
    grid.sync();

    // ---- P8: attn layer 2 fused with final projection + log_softmax ----
    for (int node = wid; node < n; node += nw)
        attn3_body(node, lane, startA, ebuf, dinv, qbuf, kv2, w2, b2, outp);
}

// ---------------------------------------------------------------------------
// Fallback path (classic multi-launch) — used only if cooperative launch fails
// ---------------------------------------------------------------------------
__global__ void k_count(const int* __restrict__ col, int* __restrict__ counts, int E) {
    int e = blockIdx.x * blockDim.x + threadIdx.x;
    if (e < E) atomicAdd(&counts[col[e]], 1);
}

__global__ __launch_bounds__(1024) void k_scan(const int* __restrict__ counts,
                                               int* __restrict__ start,
                                               float* __restrict__ dinv, int n) {
    __shared__ int wsum[16];
    int tid = threadIdx.x;
    int lane = tid & 63, wvi = tid >> 6;
    int ipt = (n + 1023) >> 10;
    int c0 = tid * ipt;
    int c1 = min(n, c0 + ipt);
    int s = 0;
    for (int i = c0; i < c1; ++i) s += counts[i];
    int x = s;
#pragma unroll
    for (int off = 1; off < 64; off <<= 1) {
        int y = __shfl_up(x, off);
        if (lane >= off) x += y;
    }
    if (lane == 63) wsum[wvi] = x;
    __syncthreads();
    if (wvi == 0 && lane < 16) {
        int t2 = wsum[lane];
#pragma unroll
        for (int off = 1; off < 16; off <<= 1) {
            int y = __shfl_up(t2, off);
            if (lane >= off) t2 += y;
        }
        wsum[lane] = t2;
    }
    __syncthreads();
    int waveoff = (wvi > 0) ? wsum[wvi - 1] : 0;
    int run = waveoff + x - s;
    for (int i = c0; i < c1; ++i) {
        int v = counts[i];
        start[i] = run;
        dinv[i] = rsqrtf((float)(v + 1));
        run += v;
    }
    if (tid == 0) start[n] = wsum[15];
}

__global__ void k_scatter(const int* __restrict__ ei, const int* __restrict__ start,
                          int* __restrict__ fill, int* __restrict__ ebuf, int E) {
    int e = blockIdx.x * blockDim.x + threadIdx.x;
    if (e >= E) return;
    int r = ei[e], c = ei[E + e];
    int pos = start[c] + atomicAdd(&fill[c], 1);
    ebuf[pos] = r;
}

__global__ __launch_bounds__(256, 4) void k_lin1(
    const float* __restrict__ x, const float* __restrict__ w,
    const float* __restrict__ b, const float* __restrict__ wv0,
    const float* __restrict__ bv0, unsigned short* __restrict__ h,
    unsigned short* __restrict__ kv, int n) {
    __shared__ __align__(16) unsigned short Alds[64 * ALD];
    __shared__ __align__(16) unsigned short Wt[64 * ALD];
    lin1_tile_body(x, w, b, wv0, bv0, h, kv, n, blockIdx.x * 64, threadIdx.x, Alds, Wt);
}

__global__ __launch_bounds__(256, 4) void k_qkv(
    const unsigned short* __restrict__ xsbase,
    const float* __restrict__ wq, const float* __restrict__ bq,
    const float* __restrict__ wk, const float* __restrict__ bk,
    const float* __restrict__ wv, const float* __restrict__ bv,
    float* __restrict__ q, unsigned short* __restrict__ kv,
    int n, int layer, int t, int kv_stride) {
    int job = blockIdx.y;
    const unsigned short* src; const float* w; const float* b; bool relu_in;
    int kv_off = 0; float* qd = nullptr;
    if (job == 0) {
        src = xsbase + (size_t)layer * n * 64;
        w = wq + layer * 4096; b = bq + layer * 64;
        relu_in = (layer >= 1); qd = q;
    } else if (job <= t) {
        int s = job - 1;
        src = xsbase + (size_t)s * n * 64;
        w = wk + layer * 4096; b = bk + layer * 64;
        kv_off = s * 128;
        relu_in = (s >= 1);
    } else {
        int s = job - t - 1;
        src = xsbase + (size_t)s * n * 64;
        w = wv + layer * 4096; b = bv + layer * 64;
        kv_off = s * 128 + 64;
        relu_in = (s >= 1);
    }
    __shared__ __align__(16) unsigned short Alds[64 * ALD];
    __shared__ __align__(16) unsigned short Wt[64 * ALD];
    qkv_tile_body(src, w, b, qd, kv, kv_stride, kv_off, relu_in,
                  blockIdx.x * 64, n, threadIdx.x, Alds, Wt);
}

template <int T>
__global__ __launch_bounds__(256) void k_attn_g(
    const int* __restrict__ start, const int* __restrict__ ebuf,
    const float* __restrict__ dinv, const float* __restrict__ q,
    const unsigned short* __restrict__ kv, unsigned short* __restrict__ outp, int n) {
    int node = (int)((blockIdx.x * (size_t)blockDim.x + threadIdx.x) >> 6);
    if (node >= n) return;
    attn_body<T>(node, threadIdx.x & 63, start, ebuf, dinv, q, kv, outp);
}

__global__ __launch_bounds__(256) void k_attn3f(
    const int* __restrict__ start, const int* __restrict__ ebuf,
    const float* __restrict__ dinv, const float* __restrict__ q,
    const unsigned short* __restrict__ kv,
    const float* __restrict__ w2, const float* __restrict__ b2,
    float* __restrict__ outp, int n) {
    int node = (int)((blockIdx.x * (size_t)blockDim.x + threadIdx.x) >> 6);
    if (node >= n) return;
    attn3_body(node, threadIdx.x & 63, start, ebuf, dinv, q, kv, w2, b2, outp);
}

// ---------------------------------------------------------------------------
extern "C" void kernel_launch(void* const* d_in, const int* in_sizes, int n_in,
                              void* d_out, int out_size, void* d_ws, size_t ws_size,
                              hipStream_t stream) {
    const float* x  = (const float*)d_in[0];
    const int*   ei = (const int*)d_in[1];
    const float* w1 = (const float*)d_in[2];
    const float* b1 = (const float*)d_in[3];
    const float* wq = (const float*)d_in[4];
    const float* bq = (const float*)d_in[5];
    const float* wk = (const float*)d_in[6];
    const float* bk = (const float*)d_in[7];
    const float* wv = (const float*)d_in[8];
    const float* bv = (const float*)d_in[9];
    const float* w2 = (const float*)d_in[10];
    const float* b2 = (const float*)d_in[11];
    float* outp = (float*)d_out;

    int n = in_sizes[0] / 256;
    int E = in_sizes[1] / 2;

    float* ws = (float*)d_ws;
    size_t off = 0;
    float* dinv = ws + off; off += (size_t)n;
    float* q    = ws + off; off += (size_t)n * 64;
    unsigned short* xsU = (unsigned short*)(ws + off); off += (size_t)n * 96;   // 3 slices bf16
    unsigned short* kv0 = (unsigned short*)(ws + off); off += (size_t)n * 32;   // n*64 bf16
    unsigned short* kv1 = (unsigned short*)(ws + off); off += (size_t)n * 128;  // n*256 bf16
    unsigned short* kv2 = (unsigned short*)(ws + off); off += (size_t)n * 192;  // n*384 bf16
    int* wsI    = (int*)(ws + off);
    int* counts = wsI;                 // n
    int* fill   = wsI + n;             // n
    int* startA = wsI + 2 * n;         // n+1
    int* ebuf   = wsI + 3 * n + 1;     // E

    // One-time: size the cooperative grid to exactly the co-resident capacity.
    static int NB = -1;
    if (NB < 0) {
        int dev = 0;
        (void)hipGetDevice(&dev);
        int nCU = 0;
        if (hipDeviceGetAttribute(&nCU, hipDeviceAttributeMultiprocessorCount, dev)
                != hipSuccess || nCU <= 0)
            nCU = 256;
        int perCU = 0;
        if (hipOccupancyMaxActiveBlocksPerMultiprocessor(
                &perCU, reinterpret_cast<const void*>(k_mega), 256, 0) != hipSuccess ||
            perCU < 1)
            perCU = 1;
        NB = nCU * perCU;
        if (NB > 2048) NB = 2048;
        if (NB < 64) NB = 64;
    }

    void* kargs[] = {
        (void*)&x, (void*)&ei, (void*)&w1, (void*)&b1, (void*)&wq, (void*)&bq,
        (void*)&wk, (void*)&bk, (void*)&wv, (void*)&bv, (void*)&w2, (void*)&b2,
        (void*)&outp, (void*)&dinv, (void*)&q, (void*)&xsU, (void*)&kv0,
        (void*)&kv1, (void*)&kv2, (void*)&counts, (void*)&fill, (void*)&startA,
        (void*)&ebuf, (void*)&n, (void*)&E};
    hipError_t err = hipLaunchCooperativeKernel(
        reinterpret_cast<const void*>(k_mega), dim3(NB), dim3(256), kargs, 0, stream);
    if (err == hipSuccess) return;
    (void)hipGetLastError();  // clear; fall through to classic path

    // ---------------- fallback: classic multi-launch pipeline ----------------
    hipMemsetAsync(counts, 0, 2 * (size_t)n * sizeof(int), stream);
    k_count<<<(E + 255) / 256, 256, 0, stream>>>(ei + E, counts, E);
    k_scan<<<1, 1024, 0, stream>>>(counts, startA, dinv, n);
    k_scatter<<<(E + 255) / 256, 256, 0, stream>>>(ei, startA, fill, ebuf, E);

    k_lin1<<<(n + 63) / 64, 256, 0, stream>>>(x, w1, b1, wv, bv, xsU, kv0, n);

    int attn_grid = (int)(((size_t)n * 64 + 255) / 256);

    k_attn_g<1><<<attn_grid, 256, 0, stream>>>(startA, ebuf, dinv, q, kv0,
                                               xsU + (size_t)n * 64, n);
    {
        dim3 grid((n + 63) / 64, 5);
        k_qkv<<<grid, 256, 0, stream>>>(xsU, wq, bq, wk, bk, wv, bv,
                                        q, kv1, n, 1, 2, 256);
        k_attn_g<2><<<attn_grid, 256, 0, stream>>>(startA, ebuf, dinv, q, kv1,
                                                   xsU + (size_t)n * 128, n);
    }
    {
        dim3 grid((n + 63) / 64, 7);
        k_qkv<<<grid, 256, 0, stream>>>(xsU, wq, bq, wk, bk, wv, bv,
                                        q, kv2, n, 2, 3, 384);
        k_attn3f<<<attn_grid, 256, 0, stream>>>(startA, ebuf, dinv, q, kv2,
                                                w2, b2, outp, n);
    }
}

// Round 2
// 499.657 us; speedup vs baseline: 1.6915x; 1.6915x over previous
//
#include <hip/hip_runtime.h>
#include <math.h>

#define HID 64
#define HEADS 8
#define ALD 72

typedef __attribute__((ext_vector_type(8))) short bf16x8;
typedef __attribute__((ext_vector_type(4))) float f32x4;

// ---------------------------------------------------------------------------
// bf16 helpers (storage compression; accumulation stays f32)
// ---------------------------------------------------------------------------
__device__ __forceinline__ unsigned short f2bf(float f) {
    union { float f; unsigned int u; } cv; cv.f = f;
    unsigned int u = cv.u;
    unsigned int r = (u + 0x7FFFu + ((u >> 16) & 1u)) >> 16;  // RNE
    return (unsigned short)r;
}
__device__ __forceinline__ float bflo(unsigned int u) {
    union { unsigned int u; float f; } cv; cv.u = u << 16; return cv.f;
}
__device__ __forceinline__ float bfhi(unsigned int u) {
    union { unsigned int u; float f; } cv; cv.u = u & 0xFFFF0000u; return cv.f;
}

__device__ __forceinline__ float dot8(const float* qp, uint4 u) {
    return qp[0] * bflo(u.x) + qp[1] * bfhi(u.x) + qp[2] * bflo(u.y) +
           qp[3] * bfhi(u.y) + qp[4] * bflo(u.z) + qp[5] * bfhi(u.z) +
           qp[6] * bflo(u.w) + qp[7] * bfhi(u.w);
}
__device__ __forceinline__ void axpy8(float a, uint4 u, float* Y) {
    Y[0] += a * bflo(u.x); Y[1] += a * bfhi(u.x);
    Y[2] += a * bflo(u.y); Y[3] += a * bfhi(u.y);
    Y[4] += a * bflo(u.z); Y[5] += a * bfhi(u.z);
    Y[6] += a * bflo(u.w); Y[7] += a * bfhi(u.w);
}

// ---------------------------------------------------------------------------
// CSR build: counts (atomic), single-block scan (+dinv), scatter
// ---------------------------------------------------------------------------
__global__ void k_count(const int* __restrict__ col, int* __restrict__ counts, int E) {
    int e = blockIdx.x * blockDim.x + threadIdx.x;
    if (e < E) atomicAdd(&counts[col[e]], 1);
}

__global__ __launch_bounds__(1024) void k_scan(const int* __restrict__ counts,
                                               int* __restrict__ start,
                                               float* __restrict__ dinv, int n) {
    __shared__ int wsum[16];
    int tid = threadIdx.x;
    int lane = tid & 63, wvi = tid >> 6;
    int ipt = (n + 1023) >> 10;
    int c0 = tid * ipt;
    int c1 = min(n, c0 + ipt);
    int s = 0;
    for (int i = c0; i < c1; ++i) s += counts[i];
    int x = s;
#pragma unroll
    for (int off = 1; off < 64; off <<= 1) {
        int y = __shfl_up(x, off);
        if (lane >= off) x += y;
    }
    if (lane == 63) wsum[wvi] = x;
    __syncthreads();
    if (wvi == 0 && lane < 16) {
        int t2 = wsum[lane];
#pragma unroll
        for (int off = 1; off < 16; off <<= 1) {
            int y = __shfl_up(t2, off);
            if (lane >= off) t2 += y;
        }
        wsum[lane] = t2;
    }
    __syncthreads();
    int waveoff = (wvi > 0) ? wsum[wvi - 1] : 0;
    int run = waveoff + x - s;
    for (int i = c0; i < c1; ++i) {
        int v = counts[i];
        start[i] = run;
        dinv[i] = rsqrtf((float)(v + 1));  // +1 self-loop
        run += v;
    }
    if (tid == 0) start[n] = wsum[15];
}

__global__ void k_scatter(const int* __restrict__ ei, const int* __restrict__ start,
                          int* __restrict__ fill, int* __restrict__ ebuf, int E) {
    int e = blockIdx.x * blockDim.x + threadIdx.x;
    if (e >= E) return;
    int r = ei[e], c = ei[E + e];
    int pos = start[c] + atomicAdd(&fill[c], 1);
    ebuf[pos] = r;
}

// ---------------------------------------------------------------------------
// lin1: h = relu(x @ W1 + b1) -> bf16 xs slice 0 (post-relu).
// MFMA 64x64 tile, 4 waves, K=256 in 4 chunks.
// ---------------------------------------------------------------------------
__device__ __forceinline__ void stage_w_bf16(unsigned short* Wt,
                                             const float* __restrict__ w, int tid) {
    for (int idx = tid; idx < 1024; idx += 256) {
        int k = idx >> 4, n4 = (idx & 15) * 4;
        float4 wv = *(const float4*)&w[k * 64 + n4];
        Wt[(n4 + 0) * ALD + k] = f2bf(wv.x);
        Wt[(n4 + 1) * ALD + k] = f2bf(wv.y);
        Wt[(n4 + 2) * ALD + k] = f2bf(wv.z);
        Wt[(n4 + 3) * ALD + k] = f2bf(wv.w);
    }
}

__device__ __forceinline__ void mfma_step(const unsigned short* Alds,
                                          const unsigned short* Wt,
                                          int tid, f32x4 acc[4]) {
    int lane = tid & 63;
    int m0 = (tid >> 6) * 16;
    int c16 = lane & 15, quad = lane >> 4;
    const unsigned short* ar = &Alds[(m0 + c16) * ALD + quad * 8];
    bf16x8 a0 = *(const bf16x8*)ar;
    bf16x8 a1 = *(const bf16x8*)(ar + 32);
#pragma unroll
    for (int nt = 0; nt < 4; ++nt) {
        const unsigned short* br = &Wt[(nt * 16 + c16) * ALD + quad * 8];
        bf16x8 b0 = *(const bf16x8*)br;
        bf16x8 b1 = *(const bf16x8*)(br + 32);
        acc[nt] = __builtin_amdgcn_mfma_f32_16x16x32_bf16(a0, b0, acc[nt], 0, 0, 0);
        acc[nt] = __builtin_amdgcn_mfma_f32_16x16x32_bf16(a1, b1, acc[nt], 0, 0, 0);
    }
}

__global__ __launch_bounds__(256, 4) void k_lin1(
    const float* __restrict__ x, const float* __restrict__ w,
    const float* __restrict__ b, unsigned short* __restrict__ h, int n) {
    __shared__ __align__(16) unsigned short Alds[64 * ALD];
    __shared__ __align__(16) unsigned short Wt[64 * ALD];
    int tid = threadIdx.x;
    int node0 = blockIdx.x * 64;
    f32x4 acc[4];
#pragma unroll
    for (int nt = 0; nt < 4; ++nt) acc[nt] = (f32x4){0.f, 0.f, 0.f, 0.f};

    for (int kc = 0; kc < 256; kc += 64) {
        __syncthreads();
        stage_w_bf16(Wt, w + kc * 64, tid);
        for (int idx = tid; idx < 1024; idx += 256) {
            int r = idx >> 4, c4 = (idx & 15) * 4;
            int node = node0 + r;
            float4 v = make_float4(0.f, 0.f, 0.f, 0.f);
            if (node < n) v = *(const float4*)&x[(size_t)node * 256 + kc + c4];
            Alds[r * ALD + c4 + 0] = f2bf(v.x);
            Alds[r * ALD + c4 + 1] = f2bf(v.y);
            Alds[r * ALD + c4 + 2] = f2bf(v.z);
            Alds[r * ALD + c4 + 3] = f2bf(v.w);
        }
        __syncthreads();
        mfma_step(Alds, Wt, tid, acc);
    }
    int lane = tid & 63;
    int m0 = (tid >> 6) * 16, c16 = lane & 15, quad = lane >> 4;
    float bias[4];
#pragma unroll
    for (int nt = 0; nt < 4; ++nt) bias[nt] = b[nt * 16 + c16];
#pragma unroll
    for (int i = 0; i < 4; ++i) {
        int node = node0 + m0 + quad * 4 + i;
        if (node < n) {
#pragma unroll
            for (int nt = 0; nt < 4; ++nt)
                h[(size_t)node * 64 + nt * 16 + c16] =
                    f2bf(fmaxf(acc[nt][i] + bias[nt], 0.f));
        }
    }
}

// ---------------------------------------------------------------------------
// Attention layer with deferred Wk/Wv:
//   Q'_h = isd * Wk_h^T (x_dst@Wq + bq)_h  (per node, in-register; bk cancels
//   in softmax over t).  Per edge gather ONLY the T raw x_t rows (bf16,
//   post-relu).  Per-head accumulate Y_h = sum_e wgt_h sum_t a_t,h x_t(src)
//   (8 f32/lane: lane (h=lane>>3, j=lane&7) holds Y_h[ch j*8..j*8+7]).
//   Epilogue: out_o = relu(dc*(Y_h . Wv[:,o] + bv_o*S)), o = lane; optionally
//   chained into final projection W2 + log_softmax (FINAL).
// One wave per node.
// ---------------------------------------------------------------------------
template <int T, bool FINAL>
__device__ __forceinline__ void attn_x_body(
    int node, int lane, const int* __restrict__ start,
    const int* __restrict__ ebuf, const float* __restrict__ dinv,
    unsigned short* __restrict__ xs, size_t sstride,
    const float* __restrict__ wq, const float* __restrict__ bq,
    const float* __restrict__ wk, const float* __restrict__ wv,
    const float* __restrict__ bv, const float* __restrict__ w2,
    const float* __restrict__ b2, float* __restrict__ outf) {
    const int h8 = lane & 56;  // head*8
    const int cb = (lane & 7) * 8;

    float qp[8];
    if (T > 1) {
        const float isd = 0.35355339059327373f;  // 1/sqrt(8)
        // q_o = bq_o + x_dst . Wq[:,o]  (o = lane), x_dst = slice T-1 row
        uint4 xu = *(const uint4*)&xs[(size_t)(T - 1) * sstride +
                                      (size_t)node * 64 + cb];
        float xq[8] = {bflo(xu.x), bfhi(xu.x), bflo(xu.y), bfhi(xu.y),
                       bflo(xu.z), bfhi(xu.z), bflo(xu.w), bfhi(xu.w)};
        float qo = bq[lane];
#pragma unroll
        for (int c = 0; c < 64; ++c)
            qo += __shfl(xq[c & 7], c >> 3) * wq[c * 64 + lane];
        float qh[8];
#pragma unroll
        for (int d = 0; d < 8; ++d) qh[d] = __shfl(qo, h8 + d);
#pragma unroll
        for (int dp = 0; dp < 8; ++dp) {
            const float* wr = &wk[(cb + dp) * 64 + h8];
            float s = 0.f;
#pragma unroll
            for (int d = 0; d < 8; ++d) s += qh[d] * wr[d];
            qp[dp] = s * isd;
        }
    }

    float dc = dinv[node];
    int s0 = start[node];
    int cnt = start[node + 1] - s0 + 1;

    float Y[8];
#pragma unroll
    for (int d = 0; d < 8; ++d) Y[d] = 0.f;
    float S = 0.f;

    for (int idx = 0; idx < cnt; ++idx) {
        int r = node;
        if (idx > 0) r = ebuf[s0 + idx - 1];
        float dr = dinv[r];
        uint4 xu[T];
#pragma unroll
        for (int t = 0; t < T; ++t)
            xu[t] = *(const uint4*)&xs[(size_t)t * sstride + (size_t)r * 64 + cb];
        float coef[T];
        if (T > 1) {
            float p[T];
#pragma unroll
            for (int t = 0; t < T; ++t) p[t] = dot8(qp, xu[t]);
#pragma unroll
            for (int off = 1; off < 8; off <<= 1) {
#pragma unroll
                for (int t = 0; t < T; ++t) p[t] += __shfl_xor(p[t], off);
            }
            float m = p[0];
#pragma unroll
            for (int t = 1; t < T; ++t) m = fmaxf(m, p[t]);
            float denom = 0.f;
#pragma unroll
            for (int t = 0; t < T; ++t) { coef[t] = __expf(p[t] - m); denom += coef[t]; }
            float w = dr / denom;
#pragma unroll
            for (int t = 0; t < T; ++t) coef[t] *= w;
        } else {
            coef[0] = dr;
        }
#pragma unroll
        for (int t = 0; t < T; ++t) axpy8(coef[t], xu[t], Y);
        S += dr;
    }

    // epilogue: out_o = relu(dc*(Y_h . Wv[:,o] + bv_o * S)), o = lane
    float v = bv[lane] * S;
#pragma unroll
    for (int c = 0; c < 64; ++c)
        v += __shfl(Y[c & 7], h8 | (c >> 3)) * wv[c * 64 + lane];
    float out = fmaxf(v * dc, 0.f);

    if (!FINAL) {
        xs[(size_t)T * sstride + (size_t)node * 64 + lane] = f2bf(out);
    } else {
        float lg = b2[lane];
#pragma unroll
        for (int c = 0; c < 64; ++c)
            lg += __shfl(out, c) * w2[c * 64 + lane];
        float mx = lg;
#pragma unroll
        for (int off = 1; off < 64; off <<= 1) mx = fmaxf(mx, __shfl_xor(mx, off));
        float e = __expf(lg - mx);
        float ssum = e;
#pragma unroll
        for (int off = 1; off < 64; off <<= 1) ssum += __shfl_xor(ssum, off);
        outf[(size_t)node * 64 + lane] = lg - mx - __logf(ssum);
    }
}

template <int T, bool FINAL>
__global__ __launch_bounds__(256, 4) void k_attn_x(
    const int* __restrict__ start, const int* __restrict__ ebuf,
    const float* __restrict__ dinv, unsigned short* __restrict__ xs,
    size_t sstride, const float* __restrict__ wq, const float* __restrict__ bq,
    const float* __restrict__ wk, const float* __restrict__ wv,
    const float* __restrict__ bv, const float* __restrict__ w2,
    const float* __restrict__ b2, float* __restrict__ outf, int n) {
    int node = (int)((blockIdx.x * (size_t)blockDim.x + threadIdx.x) >> 6);
    if (node >= n) return;
    attn_x_body<T, FINAL>(node, threadIdx.x & 63, start, ebuf, dinv, xs, sstride,
                          wq, bq, wk, wv, bv, w2, b2, outf);
}

// ---------------------------------------------------------------------------
extern "C" void kernel_launch(void* const* d_in, const int* in_sizes, int n_in,
                              void* d_out, int out_size, void* d_ws, size_t ws_size,
                              hipStream_t stream) {
    const float* x  = (const float*)d_in[0];
    const int*   ei = (const int*)d_in[1];
    const float* w1 = (const float*)d_in[2];
    const float* b1 = (const float*)d_in[3];
    const float* wq = (const float*)d_in[4];
    const float* bq = (const float*)d_in[5];
    const float* wk = (const float*)d_in[6];
    const float* bk = (const float*)d_in[7];  // cancels in softmax; unused
    const float* wv = (const float*)d_in[8];
    const float* bv = (const float*)d_in[9];
    const float* w2 = (const float*)d_in[10];
    const float* b2 = (const float*)d_in[11];
    float* outp = (float*)d_out;
    (void)bk;

    int n = in_sizes[0] / 256;
    int E = in_sizes[1] / 2;

    float* ws = (float*)d_ws;
    size_t off = 0;
    float* dinv = ws + off; off += (size_t)n;
    unsigned short* xsU = (unsigned short*)(ws + off); off += (size_t)n * 96;  // 3 slices bf16
    int* wsI    = (int*)(ws + off);
    int* counts = wsI;                 // n
    int* fill   = wsI + n;             // n
    int* startA = wsI + 2 * n;         // n+1
    int* ebuf   = wsI + 3 * n + 1;     // E

    size_t sstride = (size_t)n * 64;

    // CSR build
    hipMemsetAsync(counts, 0, 2 * (size_t)n * sizeof(int), stream);
    k_count<<<(E + 255) / 256, 256, 0, stream>>>(ei + E, counts, E);
    k_scan<<<1, 1024, 0, stream>>>(counts, startA, dinv, n);
    k_scatter<<<(E + 255) / 256, 256, 0, stream>>>(ei, startA, fill, ebuf, E);

    // lin1 -> xs slice 0 (post-relu bf16)
    k_lin1<<<(n + 63) / 64, 256, 0, stream>>>(x, w1, b1, xsU, n);

    int attn_grid = (int)(((size_t)n * 64 + 255) / 256);

    // layer 0: T=1 (no scores), Wv[0]/bv[0] deferred to epilogue
    k_attn_x<1, false><<<attn_grid, 256, 0, stream>>>(
        startA, ebuf, dinv, xsU, sstride, nullptr, nullptr, nullptr,
        wv, bv, nullptr, nullptr, nullptr, n);

    // layer 1: T=2
    k_attn_x<2, false><<<attn_grid, 256, 0, stream>>>(
        startA, ebuf, dinv, xsU, sstride, wq + 4096, bq + 64, wk + 4096,
        wv + 4096, bv + 64, nullptr, nullptr, nullptr, n);

    // layer 2: T=3, fused final projection + log_softmax
    k_attn_x<3, true><<<attn_grid, 256, 0, stream>>>(
        startA, ebuf, dinv, xsU, sstride, wq + 8192, bq + 128, wk + 8192,
        wv + 8192, bv + 128, w2, b2, outp, n);
}

// Round 3
// 285.726 us; speedup vs baseline: 2.9579x; 1.7487x over previous
//
#include <hip/hip_runtime.h>
#include <math.h>

#define HID 64
#define HEADS 8
#define ALD 72

typedef __attribute__((ext_vector_type(8))) short bf16x8;
typedef __attribute__((ext_vector_type(4))) float f32x4;

// ---------------------------------------------------------------------------
// bf16 helpers (storage compression; accumulation stays f32)
// ---------------------------------------------------------------------------
__device__ __forceinline__ unsigned short f2bf(float f) {
    union { float f; unsigned int u; } cv; cv.f = f;
    unsigned int u = cv.u;
    unsigned int r = (u + 0x7FFFu + ((u >> 16) & 1u)) >> 16;  // RNE
    return (unsigned short)r;
}
__device__ __forceinline__ float bflo(unsigned int u) {
    union { unsigned int u; float f; } cv; cv.u = u << 16; return cv.f;
}
__device__ __forceinline__ float bfhi(unsigned int u) {
    union { unsigned int u; float f; } cv; cv.u = u & 0xFFFF0000u; return cv.f;
}
__device__ __forceinline__ unsigned relu_pk(unsigned u) {  // relu on 2 packed bf16
    unsigned m = ((u & 0x8000u) ? 0u : 0xFFFFu) |
                 ((u & 0x80000000u) ? 0u : 0xFFFF0000u);
    return u & m;
}

// ---------------------------------------------------------------------------
// CSR build: counts (atomic), single-block scan (+dinv), scatter.
// scatter consumes counts via atomicSub (no separate fill array).
// ---------------------------------------------------------------------------
__global__ void k_count(const int* __restrict__ col, int* __restrict__ counts, int E) {
    int e = blockIdx.x * blockDim.x + threadIdx.x;
    if (e < E) atomicAdd(&counts[col[e]], 1);
}

__global__ __launch_bounds__(1024) void k_scan(const int* __restrict__ counts,
                                               int* __restrict__ start,
                                               float* __restrict__ dinv, int n) {
    __shared__ int wsum[16];
    int tid = threadIdx.x;
    int lane = tid & 63, wvi = tid >> 6;
    int ipt = (n + 1023) >> 10;
    int c0 = tid * ipt;
    int c1 = min(n, c0 + ipt);
    int s = 0;
    for (int i = c0; i < c1; ++i) s += counts[i];
    int x = s;
#pragma unroll
    for (int off = 1; off < 64; off <<= 1) {
        int y = __shfl_up(x, off);
        if (lane >= off) x += y;
    }
    if (lane == 63) wsum[wvi] = x;
    __syncthreads();
    if (wvi == 0 && lane < 16) {
        int t2 = wsum[lane];
#pragma unroll
        for (int off = 1; off < 16; off <<= 1) {
            int y = __shfl_up(t2, off);
            if (lane >= off) t2 += y;
        }
        wsum[lane] = t2;
    }
    __syncthreads();
    int waveoff = (wvi > 0) ? wsum[wvi - 1] : 0;
    int run = waveoff + x - s;
    for (int i = c0; i < c1; ++i) {
        int v = counts[i];
        start[i] = run;
        dinv[i] = rsqrtf((float)(v + 1));  // +1 self-loop
        run += v;
    }
    if (tid == 0) start[n] = wsum[15];
}

__global__ void k_scatter(const int* __restrict__ ei, const int* __restrict__ start,
                          int* __restrict__ counts, unsigned short* __restrict__ ebuf,
                          int E) {
    int e = blockIdx.x * blockDim.x + threadIdx.x;
    if (e >= E) return;
    int r = ei[e], c = ei[E + e];
    int pos = start[c] + atomicSub(&counts[c], 1) - 1;
    ebuf[pos] = (unsigned short)r;
}

// ---------------------------------------------------------------------------
// MFMA GEMM core: block = 64 nodes x 64 oc, 4 waves, wave w = 16-row strip.
// ---------------------------------------------------------------------------
__device__ __forceinline__ void stage_w_bf16(unsigned short* Wt,
                                             const float* __restrict__ w, int tid) {
    for (int idx = tid; idx < 1024; idx += 256) {
        int k = idx >> 4, n4 = (idx & 15) * 4;
        float4 wv = *(const float4*)&w[k * 64 + n4];
        Wt[(n4 + 0) * ALD + k] = f2bf(wv.x);
        Wt[(n4 + 1) * ALD + k] = f2bf(wv.y);
        Wt[(n4 + 2) * ALD + k] = f2bf(wv.z);
        Wt[(n4 + 3) * ALD + k] = f2bf(wv.w);
    }
}

__device__ __forceinline__ void mfma_step(const unsigned short* Alds,
                                          const unsigned short* Wt,
                                          int tid, f32x4 acc[4]) {
    int lane = tid & 63;
    int m0 = (tid >> 6) * 16;
    int c16 = lane & 15, quad = lane >> 4;
    const unsigned short* ar = &Alds[(m0 + c16) * ALD + quad * 8];
    bf16x8 a0 = *(const bf16x8*)ar;
    bf16x8 a1 = *(const bf16x8*)(ar + 32);
#pragma unroll
    for (int nt = 0; nt < 4; ++nt) {
        const unsigned short* br = &Wt[(nt * 16 + c16) * ALD + quad * 8];
        bf16x8 b0 = *(const bf16x8*)br;
        bf16x8 b1 = *(const bf16x8*)(br + 32);
        acc[nt] = __builtin_amdgcn_mfma_f32_16x16x32_bf16(a0, b0, acc[nt], 0, 0, 0);
        acc[nt] = __builtin_amdgcn_mfma_f32_16x16x32_bf16(a1, b1, acc[nt], 0, 0, 0);
    }
}

// ---------------------------------------------------------------------------
// lin1 (+ fused layer-0 V GEMM):
//   h  = relu(x @ W1 + b1)  -> bf16 xs slice 0
//   V0 = h @ Wv[0] + bv[0]  -> bf16 kv0 (stride 64)
// ---------------------------------------------------------------------------
__global__ __launch_bounds__(256, 4) void k_lin1(
    const float* __restrict__ x, const float* __restrict__ w,
    const float* __restrict__ b, const float* __restrict__ wv0,
    const float* __restrict__ bv0, unsigned short* __restrict__ h,
    unsigned short* __restrict__ kv, int n) {
    __shared__ __align__(16) unsigned short Alds[64 * ALD];
    __shared__ __align__(16) unsigned short Wt[64 * ALD];
    int tid = threadIdx.x;
    int node0 = blockIdx.x * 64;
    f32x4 acc[4];
#pragma unroll
    for (int nt = 0; nt < 4; ++nt) acc[nt] = (f32x4){0.f, 0.f, 0.f, 0.f};

    for (int kc = 0; kc < 256; kc += 64) {
        __syncthreads();
        stage_w_bf16(Wt, w + kc * 64, tid);
        for (int idx = tid; idx < 1024; idx += 256) {
            int r = idx >> 4, c4 = (idx & 15) * 4;
            int node = node0 + r;
            float4 v = make_float4(0.f, 0.f, 0.f, 0.f);
            if (node < n) v = *(const float4*)&x[(size_t)node * 256 + kc + c4];
            Alds[r * ALD + c4 + 0] = f2bf(v.x);
            Alds[r * ALD + c4 + 1] = f2bf(v.y);
            Alds[r * ALD + c4 + 2] = f2bf(v.z);
            Alds[r * ALD + c4 + 3] = f2bf(v.w);
        }
        __syncthreads();
        mfma_step(Alds, Wt, tid, acc);
    }
    int lane = tid & 63;
    int m0 = (tid >> 6) * 16, c16 = lane & 15, quad = lane >> 4;
    float bias[4];
#pragma unroll
    for (int nt = 0; nt < 4; ++nt) bias[nt] = b[nt * 16 + c16];

    __syncthreads();
    stage_w_bf16(Wt, wv0, tid);
#pragma unroll
    for (int i = 0; i < 4; ++i) {
        int row = m0 + quad * 4 + i;
        int node = node0 + row;
#pragma unroll
        for (int nt = 0; nt < 4; ++nt) {
            unsigned short hb = f2bf(fmaxf(acc[nt][i] + bias[nt], 0.f));
            Alds[row * ALD + nt * 16 + c16] = hb;
            if (node < n) h[(size_t)node * 64 + nt * 16 + c16] = hb;
        }
    }
    __syncthreads();
    f32x4 acc2[4];
#pragma unroll
    for (int nt = 0; nt < 4; ++nt) acc2[nt] = (f32x4){0.f, 0.f, 0.f, 0.f};
    mfma_step(Alds, Wt, tid, acc2);
    float bias2[4];
#pragma unroll
    for (int nt = 0; nt < 4; ++nt) bias2[nt] = bv0[nt * 16 + c16];
#pragma unroll
    for (int i = 0; i < 4; ++i) {
        int node = node0 + m0 + quad * 4 + i;
        if (node < n) {
#pragma unroll
            for (int nt = 0; nt < 4; ++nt)
                kv[(size_t)node * 64 + nt * 16 + c16] = f2bf(acc2[nt][i] + bias2[nt]);
        }
    }
}

// ---------------------------------------------------------------------------
// K/V staging GEMMs.  phase 0 (8 jobs): layer1 {K,V}x{s0,s1} -> kv1 (stride
// 256), layer2 {K,V}x{s0,s1} -> kv2 (stride 384).  phase 1 (2 jobs): layer2
// {K,V} s2 -> kv2.  job decode from blockIdx.y.
// ---------------------------------------------------------------------------
__global__ __launch_bounds__(256, 4) void k_stage(
    const unsigned short* __restrict__ xs, size_t sstride,
    const float* __restrict__ wk, const float* __restrict__ bk,
    const float* __restrict__ wv, const float* __restrict__ bv,
    unsigned short* __restrict__ kv1, unsigned short* __restrict__ kv2,
    int n, int phase) {
    int j = blockIdx.y;
    int layer, s, isV;
    if (phase == 0) { layer = 1 + (j >> 2); s = j & 1; isV = (j >> 1) & 1; }
    else            { layer = 2; s = 2; isV = j; }
    const unsigned short* src = xs + (size_t)s * sstride;
    const float* w = (isV ? wv : wk) + layer * 4096;
    const float* b = (isV ? bv : bk) + layer * 64;
    unsigned short* dst = (layer == 1) ? kv1 : kv2;
    int stride = (layer == 1) ? 256 : 384;
    int koff = s * 128 + (isV ? 64 : 0);
    bool relu_in = (s >= 1);

    __shared__ __align__(16) unsigned short Alds[64 * ALD];
    __shared__ __align__(16) unsigned short Wt[64 * ALD];
    int tid = threadIdx.x;
    int node0 = blockIdx.x * 64;
    stage_w_bf16(Wt, w, tid);
    for (int idx = tid; idx < 512; idx += 256) {
        int r = idx >> 3, seg = idx & 7;
        int node = node0 + r;
        uint4 u = make_uint4(0u, 0u, 0u, 0u);
        if (node < n) u = *(const uint4*)&src[(size_t)node * 64 + seg * 8];
        if (relu_in) {
            u.x = relu_pk(u.x); u.y = relu_pk(u.y);
            u.z = relu_pk(u.z); u.w = relu_pk(u.w);
        }
        *(uint4*)&Alds[r * ALD + seg * 8] = u;
    }
    __syncthreads();
    f32x4 acc[4];
#pragma unroll
    for (int nt = 0; nt < 4; ++nt) acc[nt] = (f32x4){0.f, 0.f, 0.f, 0.f};
    mfma_step(Alds, Wt, tid, acc);

    int lane = tid & 63;
    int m0 = (tid >> 6) * 16, c16 = lane & 15, quad = lane >> 4;
    float bias[4];
#pragma unroll
    for (int nt = 0; nt < 4; ++nt) bias[nt] = b[nt * 16 + c16];
#pragma unroll
    for (int i = 0; i < 4; ++i) {
        int node = node0 + m0 + quad * 4 + i;
        if (node < n) {
#pragma unroll
            for (int nt = 0; nt < 4; ++nt)
                dst[(size_t)node * stride + koff + nt * 16 + c16] =
                    f2bf(acc[nt][i] + bias[nt]);
        }
    }
}

// ---------------------------------------------------------------------------
// attention + aggregate, CSR by destination.  One wave per node.
// Lane = (edge-slot g = lane>>3, head h = lane&7): 8 edges in flight,
// lane-local dot/softmax.  q computed in-register from xs slice T-1 (layers
// 1-2) via shfl-matvec.  Next-chunk neighbor index prefetched to break the
// ebuf -> gather dependency chain.  T==1: pure dinv-weighted V gather.
// FINAL: fused final projection W2 + log_softmax.
// ---------------------------------------------------------------------------
template <int T, bool FINAL>
__global__ __launch_bounds__(256) void k_attn(
    const int* __restrict__ start, const unsigned short* __restrict__ ebuf,
    const float* __restrict__ dinv, const unsigned short* __restrict__ xs,
    size_t sstride, const unsigned short* __restrict__ kv,
    const float* __restrict__ wq, const float* __restrict__ bq,
    const float* __restrict__ w2, const float* __restrict__ b2,
    unsigned short* __restrict__ outb, float* __restrict__ outf, int n) {
    const int KVS = (T == 1) ? 64 : T * 128;
    int node = (int)((blockIdx.x * (size_t)blockDim.x + threadIdx.x) >> 6);
    int lane = threadIdx.x & 63;
    if (node >= n) return;
    int g = lane >> 3;
    int cb = (lane & 7) * 8;

    float qv[8];
    if (T > 1) {
        const float isd = 0.35355339059327373f;  // 1/sqrt(8)
        // q_o = bq_o + relu(x_dst) . Wq[:,o]  (o = lane) via shfl-matvec
        uint4 xu = *(const uint4*)&xs[(size_t)(T - 1) * sstride +
                                      (size_t)node * 64 + cb];
        float xq[8] = {fmaxf(bflo(xu.x), 0.f), fmaxf(bfhi(xu.x), 0.f),
                       fmaxf(bflo(xu.y), 0.f), fmaxf(bfhi(xu.y), 0.f),
                       fmaxf(bflo(xu.z), 0.f), fmaxf(bfhi(xu.z), 0.f),
                       fmaxf(bflo(xu.w), 0.f), fmaxf(bfhi(xu.w), 0.f)};
        float qo = bq[lane];
#pragma unroll
        for (int c = 0; c < 64; ++c)
            qo += __shfl(xq[c & 7], c >> 3) * wq[c * 64 + lane];
        // redistribute to head layout: qv[d] = q[(lane&7)*8 + d] * isd
#pragma unroll
        for (int d = 0; d < 8; ++d) qv[d] = __shfl(qo, (lane & 7) * 8 + d) * isd;
    }

    float dc = dinv[node];
    int s0 = start[node];
    int cnt = start[node + 1] - s0 + 1;

    float acc[8];
#pragma unroll
    for (int k = 0; k < 8; ++k) acc[k] = 0.f;

    int nch = (cnt + 7) >> 3;
    int idx = g;
    bool v_cur = idx < cnt;
    int r_cur = node;
    if (v_cur && idx > 0) r_cur = ebuf[s0 + idx - 1];

    for (int c = 0; c < nch; ++c) {
        // prefetch next chunk's neighbor index (breaks serial chain)
        int idxn = idx + 8;
        bool v_nxt = idxn < cnt;
        int r_nxt = node;
        if (v_nxt) r_nxt = ebuf[s0 + idxn - 1];

        float dr = v_cur ? dinv[r_cur] : 0.f;
        const unsigned short* rkv = kv + (size_t)r_cur * KVS;

        float sc[T];
        float wgt;
        if (T > 1) {
            float m = -1e30f;
#pragma unroll
            for (int s = 0; s < T; ++s) {
                uint4 ku = *(const uint4*)&rkv[s * 128 + cb];
                float p = qv[0] * bflo(ku.x) + qv[1] * bfhi(ku.x)
                        + qv[2] * bflo(ku.y) + qv[3] * bfhi(ku.y)
                        + qv[4] * bflo(ku.z) + qv[5] * bfhi(ku.z)
                        + qv[6] * bflo(ku.w) + qv[7] * bfhi(ku.w);
                sc[s] = p;
                m = fmaxf(m, p);
            }
            float denom = 0.f;
#pragma unroll
            for (int s = 0; s < T; ++s) { sc[s] = __expf(sc[s] - m); denom += sc[s]; }
            wgt = dr / denom;
        } else {
            sc[0] = 1.f;
            wgt = dr;
        }

        float mg[8];
#pragma unroll
        for (int k = 0; k < 8; ++k) mg[k] = 0.f;
#pragma unroll
        for (int s = 0; s < T; ++s) {
            uint4 vu = *(const uint4*)&rkv[((T == 1) ? 0 : s * 128 + 64) + cb];
            float wv_ = sc[s];
            mg[0] += wv_ * bflo(vu.x); mg[1] += wv_ * bfhi(vu.x);
            mg[2] += wv_ * bflo(vu.y); mg[3] += wv_ * bfhi(vu.y);
            mg[4] += wv_ * bflo(vu.z); mg[5] += wv_ * bfhi(vu.z);
            mg[6] += wv_ * bflo(vu.w); mg[7] += wv_ * bfhi(vu.w);
        }
#pragma unroll
        for (int k = 0; k < 8; ++k) acc[k] += wgt * mg[k];

        r_cur = r_nxt; v_cur = v_nxt; idx = idxn;
    }

#pragma unroll
    for (int off = 8; off < 64; off <<= 1) {
#pragma unroll
        for (int k = 0; k < 8; ++k) acc[k] += __shfl_xor(acc[k], off);
    }

    if (!FINAL) {
        if (g == 0) {
            ushort4 o0, o1;
            o0.x = f2bf(acc[0] * dc); o0.y = f2bf(acc[1] * dc);
            o0.z = f2bf(acc[2] * dc); o0.w = f2bf(acc[3] * dc);
            o1.x = f2bf(acc[4] * dc); o1.y = f2bf(acc[5] * dc);
            o1.z = f2bf(acc[6] * dc); o1.w = f2bf(acc[7] * dc);
            *(ushort4*)&outb[(size_t)node * 64 + cb] = o0;
            *(ushort4*)&outb[(size_t)node * 64 + cb + 4] = o1;
        }
    } else {
        // every lane holds the full row: channel c on lane (c>>3), reg acc[c&7]
        float lg = b2[lane];
#pragma unroll
        for (int c = 0; c < 64; ++c) {
            float xc = fmaxf(__shfl(acc[c & 7], c >> 3) * dc, 0.f);
            lg += xc * w2[c * 64 + lane];
        }
        float mx = lg;
#pragma unroll
        for (int off = 1; off < 64; off <<= 1) mx = fmaxf(mx, __shfl_xor(mx, off));
        float e = __expf(lg - mx);
        float ssum = e;
#pragma unroll
        for (int off = 1; off < 64; off <<= 1) ssum += __shfl_xor(ssum, off);
        outf[(size_t)node * 64 + lane] = lg - mx - __logf(ssum);
    }
}

// ---------------------------------------------------------------------------
extern "C" void kernel_launch(void* const* d_in, const int* in_sizes, int n_in,
                              void* d_out, int out_size, void* d_ws, size_t ws_size,
                              hipStream_t stream) {
    const float* x  = (const float*)d_in[0];
    const int*   ei = (const int*)d_in[1];
    const float* w1 = (const float*)d_in[2];
    const float* b1 = (const float*)d_in[3];
    const float* wq = (const float*)d_in[4];
    const float* bq = (const float*)d_in[5];
    const float* wk = (const float*)d_in[6];
    const float* bk = (const float*)d_in[7];
    const float* wv = (const float*)d_in[8];
    const float* bv = (const float*)d_in[9];
    const float* w2 = (const float*)d_in[10];
    const float* b2 = (const float*)d_in[11];
    float* outp = (float*)d_out;

    int n = in_sizes[0] / 256;
    int E = in_sizes[1] / 2;

    float* ws = (float*)d_ws;
    size_t off = 0;
    float* dinv = ws + off; off += (size_t)n;
    unsigned short* xsU = (unsigned short*)(ws + off); off += (size_t)n * 96;   // 3 slices bf16
    unsigned short* kv0 = (unsigned short*)(ws + off); off += (size_t)n * 32;   // n*64 bf16
    unsigned short* kv1 = (unsigned short*)(ws + off); off += (size_t)n * 128;  // n*256 bf16
    unsigned short* kv2 = (unsigned short*)(ws + off); off += (size_t)n * 192;  // n*384 bf16
    int* wsI    = (int*)(ws + off);
    int* counts = wsI;                      // n
    int* startA = wsI + n;                  // n+1
    unsigned short* ebuf = (unsigned short*)(wsI + 2 * n + 1);  // E u16

    size_t sstride = (size_t)n * 64;

    // CSR build (scatter consumes counts via atomicSub)
    hipMemsetAsync(counts, 0, (size_t)n * sizeof(int), stream);
    k_count<<<(E + 255) / 256, 256, 0, stream>>>(ei + E, counts, E);
    k_scan<<<1, 1024, 0, stream>>>(counts, startA, dinv, n);
    k_scatter<<<(E + 255) / 256, 256, 0, stream>>>(ei, startA, counts, ebuf, E);

    // lin1 + fused layer-0 V GEMM
    k_lin1<<<(n + 63) / 64, 256, 0, stream>>>(x, w1, b1, wv, bv, xsU, kv0, n);

    int attn_grid = (int)(((size_t)n * 64 + 255) / 256);
    int NT = (n + 63) / 64;

    // layer 0 attention (T=1): dinv-weighted V0 gather -> xs slice 1
    k_attn<1, false><<<attn_grid, 256, 0, stream>>>(
        startA, ebuf, dinv, xsU, sstride, kv0, nullptr, nullptr, nullptr, nullptr,
        xsU + sstride, nullptr, n);

    // stage phase 0: layer1 K/V s0,s1 + layer2 K/V s0,s1 (8 jobs)
    {
        dim3 grid(NT, 8);
        k_stage<<<grid, 256, 0, stream>>>(xsU, sstride, wk, bk, wv, bv,
                                          kv1, kv2, n, 0);
    }
    // layer 1 attention (T=2, q folded) -> xs slice 2
    k_attn<2, false><<<attn_grid, 256, 0, stream>>>(
        startA, ebuf, dinv, xsU, sstride, kv1, wq + 4096, bq + 64, nullptr, nullptr,
        xsU + 2 * sstride, nullptr, n);

    // stage phase 1: layer2 K/V s2 (2 jobs)
    {
        dim3 grid(NT, 2);
        k_stage<<<grid, 256, 0, stream>>>(xsU, sstride, wk, bk, wv, bv,
                                          kv1, kv2, n, 1);
    }
    // layer 2 attention (T=3, q folded) + final projection + log_softmax
    k_attn<3, true><<<attn_grid, 256, 0, stream>>>(
        startA, ebuf, dinv, xsU, sstride, kv2, wq + 8192, bq + 128, w2, b2,
        nullptr, outp, n);
}

// Round 4
// 269.465 us; speedup vs baseline: 3.1364x; 1.0603x over previous
//
#include <hip/hip_runtime.h>
#include <math.h>

#define HID 64
#define HEADS 8
#define ALD 72

typedef __attribute__((ext_vector_type(8))) short bf16x8;
typedef __attribute__((ext_vector_type(4))) float f32x4;

// ---------------------------------------------------------------------------
// bf16 helpers (storage compression; accumulation stays f32)
// ---------------------------------------------------------------------------
__device__ __forceinline__ unsigned short f2bf(float f) {
    union { float f; unsigned int u; } cv; cv.f = f;
    unsigned int u = cv.u;
    unsigned int r = (u + 0x7FFFu + ((u >> 16) & 1u)) >> 16;  // RNE
    return (unsigned short)r;
}
__device__ __forceinline__ float bflo(unsigned int u) {
    union { unsigned int u; float f; } cv; cv.u = u << 16; return cv.f;
}
__device__ __forceinline__ float bfhi(unsigned int u) {
    union { unsigned int u; float f; } cv; cv.u = u & 0xFFFF0000u; return cv.f;
}
__device__ __forceinline__ unsigned relu_pk(unsigned u) {  // relu on 2 packed bf16
    unsigned m = ((u & 0x8000u) ? 0u : 0xFFFFu) |
                 ((u & 0x80000000u) ? 0u : 0xFFFF0000u);
    return u & m;
}

__device__ __forceinline__ float dot8(const float* qp, uint4 u) {
    return qp[0] * bflo(u.x) + qp[1] * bfhi(u.x) + qp[2] * bflo(u.y) +
           qp[3] * bfhi(u.y) + qp[4] * bflo(u.z) + qp[5] * bfhi(u.z) +
           qp[6] * bflo(u.w) + qp[7] * bfhi(u.w);
}
__device__ __forceinline__ void axpy8(float a, uint4 u, float* Y) {
    Y[0] += a * bflo(u.x); Y[1] += a * bfhi(u.x);
    Y[2] += a * bflo(u.y); Y[3] += a * bfhi(u.y);
    Y[4] += a * bflo(u.z); Y[5] += a * bfhi(u.z);
    Y[6] += a * bflo(u.w); Y[7] += a * bfhi(u.w);
}

// ---------------------------------------------------------------------------
// CSR build: counts (atomic), single-block scan (+dinv), scatter.
// scatter consumes counts via atomicSub (restores counts to 0 afterwards).
// ---------------------------------------------------------------------------
__global__ void k_count(const int* __restrict__ col, int* __restrict__ counts, int E) {
    int e = blockIdx.x * blockDim.x + threadIdx.x;
    if (e < E) atomicAdd(&counts[col[e]], 1);
}

__global__ __launch_bounds__(1024) void k_scan(const int* __restrict__ counts,
                                               int* __restrict__ start,
                                               float* __restrict__ dinv, int n) {
    __shared__ int wsum[16];
    int tid = threadIdx.x;
    int lane = tid & 63, wvi = tid >> 6;
    int ipt = (n + 1023) >> 10;
    int c0 = tid * ipt;
    int c1 = min(n, c0 + ipt);
    int s = 0;
    for (int i = c0; i < c1; ++i) s += counts[i];
    int x = s;
#pragma unroll
    for (int off = 1; off < 64; off <<= 1) {
        int y = __shfl_up(x, off);
        if (lane >= off) x += y;
    }
    if (lane == 63) wsum[wvi] = x;
    __syncthreads();
    if (wvi == 0 && lane < 16) {
        int t2 = wsum[lane];
#pragma unroll
        for (int off = 1; off < 16; off <<= 1) {
            int y = __shfl_up(t2, off);
            if (lane >= off) t2 += y;
        }
        wsum[lane] = t2;
    }
    __syncthreads();
    int waveoff = (wvi > 0) ? wsum[wvi - 1] : 0;
    int run = waveoff + x - s;
    for (int i = c0; i < c1; ++i) {
        int v = counts[i];
        start[i] = run;
        dinv[i] = rsqrtf((float)(v + 1));  // +1 self-loop
        run += v;
    }
    if (tid == 0) start[n] = wsum[15];
}

__global__ void k_scatter(const int* __restrict__ ei, const int* __restrict__ start,
                          int* __restrict__ counts, unsigned short* __restrict__ ebuf,
                          int E) {
    int e = blockIdx.x * blockDim.x + threadIdx.x;
    if (e >= E) return;
    int r = ei[e], c = ei[E + e];
    int pos = start[c] + atomicSub(&counts[c], 1) - 1;
    ebuf[pos] = (unsigned short)r;
}

// ---------------------------------------------------------------------------
// MFMA GEMM core: block = 64 nodes x 64 oc, 4 waves, wave w = 16-row strip.
// ---------------------------------------------------------------------------
__device__ __forceinline__ void stage_w_bf16(unsigned short* Wt,
                                             const float* __restrict__ w, int tid) {
    for (int idx = tid; idx < 1024; idx += 256) {
        int k = idx >> 4, n4 = (idx & 15) * 4;
        float4 wv = *(const float4*)&w[k * 64 + n4];
        Wt[(n4 + 0) * ALD + k] = f2bf(wv.x);
        Wt[(n4 + 1) * ALD + k] = f2bf(wv.y);
        Wt[(n4 + 2) * ALD + k] = f2bf(wv.z);
        Wt[(n4 + 3) * ALD + k] = f2bf(wv.w);
    }
}

__device__ __forceinline__ void mfma_step(const unsigned short* Alds,
                                          const unsigned short* Wt,
                                          int tid, f32x4 acc[4]) {
    int lane = tid & 63;
    int m0 = (tid >> 6) * 16;
    int c16 = lane & 15, quad = lane >> 4;
    const unsigned short* ar = &Alds[(m0 + c16) * ALD + quad * 8];
    bf16x8 a0 = *(const bf16x8*)ar;
    bf16x8 a1 = *(const bf16x8*)(ar + 32);
#pragma unroll
    for (int nt = 0; nt < 4; ++nt) {
        const unsigned short* br = &Wt[(nt * 16 + c16) * ALD + quad * 8];
        bf16x8 b0 = *(const bf16x8*)br;
        bf16x8 b1 = *(const bf16x8*)(br + 32);
        acc[nt] = __builtin_amdgcn_mfma_f32_16x16x32_bf16(a0, b0, acc[nt], 0, 0, 0);
        acc[nt] = __builtin_amdgcn_mfma_f32_16x16x32_bf16(a1, b1, acc[nt], 0, 0, 0);
    }
}

// ---------------------------------------------------------------------------
// lin1 (+ fused layer-0 V GEMM):
//   h  = relu(x @ W1 + b1)  -> bf16 xs slice 0
//   V0 = h @ Wv[0] + bv[0]  -> bf16 kv0 (stride 64)
// ---------------------------------------------------------------------------
__global__ __launch_bounds__(256, 4) void k_lin1(
    const float* __restrict__ x, const float* __restrict__ w,
    const float* __restrict__ b, const float* __restrict__ wv0,
    const float* __restrict__ bv0, unsigned short* __restrict__ h,
    unsigned short* __restrict__ kv, int n) {
    __shared__ __align__(16) unsigned short Alds[64 * ALD];
    __shared__ __align__(16) unsigned short Wt[64 * ALD];
    int tid = threadIdx.x;
    int node0 = blockIdx.x * 64;
    f32x4 acc[4];
#pragma unroll
    for (int nt = 0; nt < 4; ++nt) acc[nt] = (f32x4){0.f, 0.f, 0.f, 0.f};

    for (int kc = 0; kc < 256; kc += 64) {
        __syncthreads();
        stage_w_bf16(Wt, w + kc * 64, tid);
        for (int idx = tid; idx < 1024; idx += 256) {
            int r = idx >> 4, c4 = (idx & 15) * 4;
            int node = node0 + r;
            float4 v = make_float4(0.f, 0.f, 0.f, 0.f);
            if (node < n) v = *(const float4*)&x[(size_t)node * 256 + kc + c4];
            Alds[r * ALD + c4 + 0] = f2bf(v.x);
            Alds[r * ALD + c4 + 1] = f2bf(v.y);
            Alds[r * ALD + c4 + 2] = f2bf(v.z);
            Alds[r * ALD + c4 + 3] = f2bf(v.w);
        }
        __syncthreads();
        mfma_step(Alds, Wt, tid, acc);
    }
    int lane = tid & 63;
    int m0 = (tid >> 6) * 16, c16 = lane & 15, quad = lane >> 4;
    float bias[4];
#pragma unroll
    for (int nt = 0; nt < 4; ++nt) bias[nt] = b[nt * 16 + c16];

    __syncthreads();
    stage_w_bf16(Wt, wv0, tid);
#pragma unroll
    for (int i = 0; i < 4; ++i) {
        int row = m0 + quad * 4 + i;
        int node = node0 + row;
#pragma unroll
        for (int nt = 0; nt < 4; ++nt) {
            unsigned short hb = f2bf(fmaxf(acc[nt][i] + bias[nt], 0.f));
            Alds[row * ALD + nt * 16 + c16] = hb;
            if (node < n) h[(size_t)node * 64 + nt * 16 + c16] = hb;
        }
    }
    __syncthreads();
    f32x4 acc2[4];
#pragma unroll
    for (int nt = 0; nt < 4; ++nt) acc2[nt] = (f32x4){0.f, 0.f, 0.f, 0.f};
    mfma_step(Alds, Wt, tid, acc2);
    float bias2[4];
#pragma unroll
    for (int nt = 0; nt < 4; ++nt) bias2[nt] = bv0[nt * 16 + c16];
#pragma unroll
    for (int i = 0; i < 4; ++i) {
        int node = node0 + m0 + quad * 4 + i;
        if (node < n) {
#pragma unroll
            for (int nt = 0; nt < 4; ++nt)
                kv[(size_t)node * 64 + nt * 16 + c16] = f2bf(acc2[nt][i] + bias2[nt]);
        }
    }
}

// ---------------------------------------------------------------------------
// K/V staging GEMMs.
//  phase 0 (4 jobs): layer1 {K,V} x {s0,s1}      -> kv1 (stride 256)
//  phase 1 (6 jobs): layer2 {K,V} x {s0,s1,s2}   -> kv2 (stride 384)
// Staged immediately before the attention pass that consumes them (L2 warmth).
// ---------------------------------------------------------------------------
__global__ __launch_bounds__(256, 4) void k_stage(
    const unsigned short* __restrict__ xs, size_t sstride,
    const float* __restrict__ wk, const float* __restrict__ bk,
    const float* __restrict__ wv, const float* __restrict__ bv,
    unsigned short* __restrict__ kv1, unsigned short* __restrict__ kv2,
    int n, int phase) {
    int j = blockIdx.y;
    int layer, s, isV;
    if (phase == 0) { layer = 1; s = j & 1; isV = j >> 1; }
    else            { layer = 2; s = j >> 1; isV = j & 1; }
    const unsigned short* src = xs + (size_t)s * sstride;
    const float* w = (isV ? wv : wk) + layer * 4096;
    const float* b = (isV ? bv : bk) + layer * 64;
    unsigned short* dst = (layer == 1) ? kv1 : kv2;
    int stride = (layer == 1) ? 256 : 384;
    int koff = s * 128 + (isV ? 64 : 0);
    bool relu_in = (s >= 1);

    __shared__ __align__(16) unsigned short Alds[64 * ALD];
    __shared__ __align__(16) unsigned short Wt[64 * ALD];
    int tid = threadIdx.x;
    int node0 = blockIdx.x * 64;
    stage_w_bf16(Wt, w, tid);
    for (int idx = tid; idx < 512; idx += 256) {
        int r = idx >> 3, seg = idx & 7;
        int node = node0 + r;
        uint4 u = make_uint4(0u, 0u, 0u, 0u);
        if (node < n) u = *(const uint4*)&src[(size_t)node * 64 + seg * 8];
        if (relu_in) {
            u.x = relu_pk(u.x); u.y = relu_pk(u.y);
            u.z = relu_pk(u.z); u.w = relu_pk(u.w);
        }
        *(uint4*)&Alds[r * ALD + seg * 8] = u;
    }
    __syncthreads();
    f32x4 acc[4];
#pragma unroll
    for (int nt = 0; nt < 4; ++nt) acc[nt] = (f32x4){0.f, 0.f, 0.f, 0.f};
    mfma_step(Alds, Wt, tid, acc);

    int lane = tid & 63;
    int m0 = (tid >> 6) * 16, c16 = lane & 15, quad = lane >> 4;
    float bias[4];
#pragma unroll
    for (int nt = 0; nt < 4; ++nt) bias[nt] = b[nt * 16 + c16];
#pragma unroll
    for (int i = 0; i < 4; ++i) {
        int node = node0 + m0 + quad * 4 + i;
        if (node < n) {
#pragma unroll
            for (int nt = 0; nt < 4; ++nt)
                dst[(size_t)node * stride + koff + nt * 16 + c16] =
                    f2bf(acc[nt][i] + bias[nt]);
        }
    }
}

// ---------------------------------------------------------------------------
// attention + aggregate, CSR by destination.  One wave per node.
// Lane = (edge-slot g = lane>>3, head h = lane&7): 8 edges in flight,
// lane-local dot/softmax.  q computed in the prologue from the wave-uniform
// x_dst row (HW broadcast loads, 8 parallel accumulators — NO serial shfl
// chain).  Edge loop is depth-2 software pipelined: chunk c+1's K/V rows are
// loaded into registers before chunk c's compute (2x memory parallelism).
// T==1: pure dinv-weighted V gather.  FINAL: fused W2 + log_softmax.
// ---------------------------------------------------------------------------
template <int T, bool FINAL>
__global__ __launch_bounds__(256) void k_attn(
    const int* __restrict__ start, const unsigned short* __restrict__ ebuf,
    const float* __restrict__ dinv, const unsigned short* __restrict__ xs,
    size_t sstride, const unsigned short* __restrict__ kv,
    const float* __restrict__ wq, const float* __restrict__ bq,
    const float* __restrict__ w2, const float* __restrict__ b2,
    unsigned short* __restrict__ outb, float* __restrict__ outf, int n) {
    const int KVS = (T == 1) ? 64 : T * 128;
    int node = (int)((blockIdx.x * (size_t)blockDim.x + threadIdx.x) >> 6);
    int lane = threadIdx.x & 63;
    if (node >= n) return;
    int g = lane >> 3;
    int cb = (lane & 7) * 8;

    float qv[8];
    if (T > 1) {
        const float isd = 0.35355339059327373f;  // 1/sqrt(8)
        // q_o = bq_o + relu(x_dst).Wq[:,o], o = lane.  x_dst row is wave-
        // uniform -> broadcast loads; 8 parallel accumulators (depth 8).
        const unsigned short* xrow =
            &xs[(size_t)(T - 1) * sstride + (size_t)node * 64];
        float a0 = 0.f, a1 = 0.f, a2 = 0.f, a3 = 0.f;
        float a4 = 0.f, a5 = 0.f, a6 = 0.f, a7 = 0.f;
#pragma unroll
        for (int w8 = 0; w8 < 8; ++w8) {
            uint4 u = *(const uint4*)&xrow[w8 * 8];
            const float* wc = &wq[(w8 * 8) * 64 + lane];
            a0 += fmaxf(bflo(u.x), 0.f) * wc[0 * 64];
            a1 += fmaxf(bfhi(u.x), 0.f) * wc[1 * 64];
            a2 += fmaxf(bflo(u.y), 0.f) * wc[2 * 64];
            a3 += fmaxf(bfhi(u.y), 0.f) * wc[3 * 64];
            a4 += fmaxf(bflo(u.z), 0.f) * wc[4 * 64];
            a5 += fmaxf(bfhi(u.z), 0.f) * wc[5 * 64];
            a6 += fmaxf(bflo(u.w), 0.f) * wc[6 * 64];
            a7 += fmaxf(bfhi(u.w), 0.f) * wc[7 * 64];
        }
        float qo = bq[lane] + (((a0 + a1) + (a2 + a3)) + ((a4 + a5) + (a6 + a7)));
        // redistribute to head layout: qv[d] = q[(lane&7)*8 + d] * isd
#pragma unroll
        for (int d = 0; d < 8; ++d) qv[d] = __shfl(qo, cb + d) * isd;
    }

    float dc = dinv[node];
    int s0 = start[node];
    int cnt = start[node + 1] - s0 + 1;

    float acc[8];
#pragma unroll
    for (int k = 0; k < 8; ++k) acc[k] = 0.f;

    int nch = (cnt + 7) >> 3;
    int idx = g;
    bool vc = idx < cnt;
    int rc = node;
    if (vc && idx > 0) rc = ebuf[s0 + idx - 1];
    float drc = vc ? dinv[rc] : 0.f;
    {
        const unsigned short* pc = kv + (size_t)rc * KVS;
        uint4 Kc[T], Vc[T];
#pragma unroll
        for (int s = 0; s < T; ++s) {
            if (T > 1) Kc[s] = *(const uint4*)&pc[s * 128 + cb];
            Vc[s] = *(const uint4*)&pc[((T == 1) ? 0 : s * 128 + 64) + cb];
        }

        for (int c = 0; c < nch; ++c) {
            // ---- prefetch chunk c+1 into registers (latency overlap) ----
            int idxn = idx + 8;
            bool vn = idxn < cnt;
            int rn = node;
            if (vn) rn = ebuf[s0 + idxn - 1];
            float drn = vn ? dinv[rn] : 0.f;
            const unsigned short* pn = kv + (size_t)rn * KVS;
            uint4 Kn[T], Vn[T];
#pragma unroll
            for (int s = 0; s < T; ++s) {
                if (T > 1) Kn[s] = *(const uint4*)&pn[s * 128 + cb];
                Vn[s] = *(const uint4*)&pn[((T == 1) ? 0 : s * 128 + 64) + cb];
            }

            // ---- compute on chunk c ----
            float sc[T];
            float wgt;
            if (T > 1) {
                float m = -1e30f;
#pragma unroll
                for (int s = 0; s < T; ++s) {
                    float p = dot8(qv, Kc[s]);
                    sc[s] = p;
                    m = fmaxf(m, p);
                }
                float denom = 0.f;
#pragma unroll
                for (int s = 0; s < T; ++s) {
                    sc[s] = __expf(sc[s] - m);
                    denom += sc[s];
                }
                wgt = drc / denom;
            } else {
                sc[0] = 1.f;
                wgt = drc;
            }

            float mg[8];
#pragma unroll
            for (int k = 0; k < 8; ++k) mg[k] = 0.f;
#pragma unroll
            for (int s = 0; s < T; ++s) axpy8(sc[s], Vc[s], mg);
#pragma unroll
            for (int k = 0; k < 8; ++k) acc[k] += wgt * mg[k];

            // ---- rotate ----
#pragma unroll
            for (int s = 0; s < T; ++s) {
                if (T > 1) Kc[s] = Kn[s];
                Vc[s] = Vn[s];
            }
            drc = drn;
            idx = idxn;
        }
    }

#pragma unroll
    for (int off = 8; off < 64; off <<= 1) {
#pragma unroll
        for (int k = 0; k < 8; ++k) acc[k] += __shfl_xor(acc[k], off);
    }

    if (!FINAL) {
        if (g == 0) {
            ushort4 o0, o1;
            o0.x = f2bf(acc[0] * dc); o0.y = f2bf(acc[1] * dc);
            o0.z = f2bf(acc[2] * dc); o0.w = f2bf(acc[3] * dc);
            o1.x = f2bf(acc[4] * dc); o1.y = f2bf(acc[5] * dc);
            o1.z = f2bf(acc[6] * dc); o1.w = f2bf(acc[7] * dc);
            *(ushort4*)&outb[(size_t)node * 64 + cb] = o0;
            *(ushort4*)&outb[(size_t)node * 64 + cb + 4] = o1;
        }
    } else {
        // every lane holds the full row: channel c on lane (c>>3), reg acc[c&7]
        float lg = b2[lane];
#pragma unroll
        for (int c = 0; c < 64; ++c) {
            float xc = fmaxf(__shfl(acc[c & 7], c >> 3) * dc, 0.f);
            lg += xc * w2[c * 64 + lane];
        }
        float mx = lg;
#pragma unroll
        for (int off = 1; off < 64; off <<= 1) mx = fmaxf(mx, __shfl_xor(mx, off));
        float e = __expf(lg - mx);
        float ssum = e;
#pragma unroll
        for (int off = 1; off < 64; off <<= 1) ssum += __shfl_xor(ssum, off);
        outf[(size_t)node * 64 + lane] = lg - mx - __logf(ssum);
    }
}

// ---------------------------------------------------------------------------
extern "C" void kernel_launch(void* const* d_in, const int* in_sizes, int n_in,
                              void* d_out, int out_size, void* d_ws, size_t ws_size,
                              hipStream_t stream) {
    const float* x  = (const float*)d_in[0];
    const int*   ei = (const int*)d_in[1];
    const float* w1 = (const float*)d_in[2];
    const float* b1 = (const float*)d_in[3];
    const float* wq = (const float*)d_in[4];
    const float* bq = (const float*)d_in[5];
    const float* wk = (const float*)d_in[6];
    const float* bk = (const float*)d_in[7];
    const float* wv = (const float*)d_in[8];
    const float* bv = (const float*)d_in[9];
    const float* w2 = (const float*)d_in[10];
    const float* b2 = (const float*)d_in[11];
    float* outp = (float*)d_out;

    int n = in_sizes[0] / 256;
    int E = in_sizes[1] / 2;

    float* ws = (float*)d_ws;
    size_t off = 0;
    float* dinv = ws + off; off += (size_t)n;
    unsigned short* xsU = (unsigned short*)(ws + off); off += (size_t)n * 96;   // 3 slices bf16
    unsigned short* kv0 = (unsigned short*)(ws + off); off += (size_t)n * 32;   // n*64 bf16
    unsigned short* kv1 = (unsigned short*)(ws + off); off += (size_t)n * 128;  // n*256 bf16
    unsigned short* kv2 = (unsigned short*)(ws + off); off += (size_t)n * 192;  // n*384 bf16
    int* wsI    = (int*)(ws + off);
    int* counts = wsI;                      // n
    int* startA = wsI + n;                  // n+1
    unsigned short* ebuf = (unsigned short*)(wsI + 2 * n + 1);  // E u16

    size_t sstride = (size_t)n * 64;

    // CSR build (scatter consumes counts via atomicSub)
    hipMemsetAsync(counts, 0, (size_t)n * sizeof(int), stream);
    k_count<<<(E + 255) / 256, 256, 0, stream>>>(ei + E, counts, E);
    k_scan<<<1, 1024, 0, stream>>>(counts, startA, dinv, n);
    k_scatter<<<(E + 255) / 256, 256, 0, stream>>>(ei, startA, counts, ebuf, E);

    // lin1 + fused layer-0 V GEMM
    k_lin1<<<(n + 63) / 64, 256, 0, stream>>>(x, w1, b1, wv, bv, xsU, kv0, n);

    int attn_grid = (int)(((size_t)n * 64 + 255) / 256);
    int NT = (n + 63) / 64;

    // layer 0 attention (T=1): dinv-weighted V0 gather -> xs slice 1
    k_attn<1, false><<<attn_grid, 256, 0, stream>>>(
        startA, ebuf, dinv, xsU, sstride, kv0, nullptr, nullptr, nullptr, nullptr,
        xsU + sstride, nullptr, n);

    // stage kv1 (layer1 K/V, s0,s1) right before its consumer
    {
        dim3 grid(NT, 4);
        k_stage<<<grid, 256, 0, stream>>>(xsU, sstride, wk, bk, wv, bv,
                                          kv1, kv2, n, 0);
    }
    // layer 1 attention (T=2, q in prologue) -> xs slice 2
    k_attn<2, false><<<attn_grid, 256, 0, stream>>>(
        startA, ebuf, dinv, xsU, sstride, kv1, wq + 4096, bq + 64, nullptr, nullptr,
        xsU + 2 * sstride, nullptr, n);

    // stage kv2 (layer2 K/V, s0,s1,s2) right before its consumer
    {
        dim3 grid(NT, 6);
        k_stage<<<grid, 256, 0, stream>>>(xsU, sstride, wk, bk, wv, bv,
                                          kv1, kv2, n, 1);
    }
    // layer 2 attention (T=3) + final projection + log_softmax
    k_attn<3, true><<<attn_grid, 256, 0, stream>>>(
        startA, ebuf, dinv, xsU, sstride, kv2, wq + 8192, bq + 128, w2, b2,
        nullptr, outp, n);
}